// Round 6
// baseline (219.620 us; speedup 1.0000x reference)
//
#include <hip/hip_runtime.h>
#include <math.h>

#define NPTS 262144
#define GBLK (NPTS / 128)     // 2048 gate blocks (128 points each)
#define CPE  2048             // chunks per expert in expert grid

typedef float f4v __attribute__((ext_vector_type(4)));
typedef short s8v __attribute__((ext_vector_type(8)));

static __device__ __forceinline__ unsigned short f2bf(float f) {
    unsigned u = __float_as_uint(f);
    u += 0x7fffu + ((u >> 16) & 1u);
    return (unsigned short)(u >> 16);
}
static __device__ __forceinline__ unsigned pack2(float lo, float hi) {
    return ((unsigned)f2bf(hi) << 16) | (unsigned)f2bf(lo);
}
static __device__ __forceinline__ float sinrev(float x) {   // sin(2*pi*x)
    return __builtin_amdgcn_sinf(x);
}

union BFrag { uint4 q; unsigned u[4]; s8v s; };

// ---------------- prep: pack A-fragments (pre-scaled bf16 weights) + scaled biases ----------------
__global__ __launch_bounds__(256) void prep_kernel(
    const float* __restrict__ we0, const float* __restrict__ be0,
    const float* __restrict__ wm, const float* __restrict__ bm,
    uint4* __restrict__ packA, float* __restrict__ biasS)
{
    const int idx = blockIdx.x * 256 + threadIdx.x;
    const float PI2I = 0.15915494309189535f;
    if (idx < 12288) {
        const int l = idx & 63;
        const int fr = (idx >> 6) & 7;
        const int grp = idx >> 9;            // e*3 + ell
        const int e = grp / 3, ell = grp % 3;
        const int tau = fr >> 1, ks = fr & 1;
        const int g = l >> 4, m = l & 15;
        const int row = tau * 16 + m;
        const float scale = (ell == 0) ? (22.5f + 45.0f * (float)e) * PI2I : 30.0f * PI2I;
        const float* W = (ell == 0) ? (we0 + e * 4096) : (wm + ((ell - 1) * 8 + e) * 4096);
        unsigned short v[8];
#pragma unroll
        for (int i = 0; i < 8; i++) {
            const int k = 32 * ks + 4 * g + (i < 4 ? i : i + 12);
            v[i] = f2bf(W[row * 64 + k] * scale);
        }
        uint4 q;
        q.x = (unsigned)v[0] | ((unsigned)v[1] << 16);
        q.y = (unsigned)v[2] | ((unsigned)v[3] << 16);
        q.z = (unsigned)v[4] | ((unsigned)v[5] << 16);
        q.w = (unsigned)v[6] | ((unsigned)v[7] << 16);
        packA[idx] = q;
    } else if (idx < 12288 + 1536) {
        const int j = idx - 12288;           // e*192 + ell*64 + r
        const int r = j & 63;
        const int grp = j >> 6;
        const int e = grp / 3, ell = grp % 3;
        const float scale = (ell == 0) ? (22.5f + 45.0f * (float)e) * PI2I : 30.0f * PI2I;
        const float b = (ell == 0) ? be0[e * 64 + r] : bm[((ell - 1) * 8 + e) * 64 + r];
        biasS[j] = b * scale;
    }
}

// ---------------- K1: gate — weights via scalar loads (uniform rows), no weight LDS ----------------
// 256 threads = 4 waves; waves {0,1} handle points 0..63 (halves 0/1), waves {2,3} points 64..127.
// half is wave-uniform (readfirstlane) so all gw1/gw2 row addresses are scalar (s_load, L1-served).
__global__ __launch_bounds__(256) void gate_kernel(
    const float* __restrict__ coords,
    const float* __restrict__ fw, const float* __restrict__ fb,
    const float* __restrict__ gw1, const float* __restrict__ gb1,
    const float* __restrict__ lng, const float* __restrict__ lnb,
    const float* __restrict__ gw2, const float* __restrict__ gb2,
    unsigned char* __restrict__ sel, int* __restrict__ blkcnt)
{
    __shared__ float s_mu[2][128];
    __shared__ float s_v[2][128];
    __shared__ float s_lg[2][128][8];
    __shared__ int s_cnt[8];

    const int t = threadIdx.x;
    const int lane = t & 63;
    const int half = __builtin_amdgcn_readfirstlane((t >> 6) & 1);  // wave-uniform SGPR
    const int p = lane + 64 * (t >> 7);          // block-local point 0..127
    const int n = blockIdx.x * 128 + p;
    if (t < 8) s_cnt[t] = 0;

    const float c0 = coords[n * 3], c1 = coords[n * 3 + 1], c2 = coords[n * 3 + 2];
    float f[64];
#pragma unroll
    for (int j = 0; j < 64; j++)
        f[j] = fb[j] + c0 * fw[j * 3] + c1 * fw[j * 3 + 1] + c2 * fw[j * 3 + 2];

    const int rbase = 32 * half;                 // uniform
    float gg[32];
    float mupart = 0.f;
#pragma unroll
    for (int j = 0; j < 32; j++) {
        const int row = rbase + j;               // uniform
        float a = gb1[row];
#pragma unroll
        for (int k = 0; k < 64; k += 4) {
            const float4 w = *(const float4*)&gw1[row * 64 + k];   // s_load_dwordx4 (uniform)
            a += f[k] * w.x + f[k + 1] * w.y + f[k + 2] * w.z + f[k + 3] * w.w;
        }
        gg[j] = a; mupart += a;
    }
    s_mu[half][p] = mupart;
    __syncthreads();
    const float mu = (s_mu[0][p] + s_mu[1][p]) * (1.f / 64.f);
    float vpart = 0.f;
#pragma unroll
    for (int j = 0; j < 32; j++) { const float d = gg[j] - mu; vpart += d * d; }
    s_v[half][p] = vpart;
    __syncthreads();
    const float var = (s_v[0][p] + s_v[1][p]) * (1.f / 64.f);
    const float rs = rsqrtf(var + 1e-5f);

    float lp[8];
#pragma unroll
    for (int e = 0; e < 8; e++) lp[e] = 0.f;
#pragma unroll
    for (int j = 0; j < 32; j++) {
        const int row = rbase + j;               // uniform
        const float gn = (gg[j] - mu) * rs * lng[row] + lnb[row];
#pragma unroll
        for (int e = 0; e < 8; e++) lp[e] += gn * gw2[e * 64 + row];   // uniform gw2 reads
    }
#pragma unroll
    for (int e = 0; e < 8; e++) s_lg[half][p][e] = lp[e];
    __syncthreads();

    unsigned mbits = 0;
    if (half == 0) {
        float logit[8];
#pragma unroll
        for (int e = 0; e < 8; e++) logit[e] = s_lg[0][p][e] + s_lg[1][p][e] + gb2[e];
        // top-2 (reference tie semantics: selected iff logit >= 2nd largest)
        float m1 = logit[0]; int i1 = 0;
#pragma unroll
        for (int e = 1; e < 8; e++) if (logit[e] > m1) { m1 = logit[e]; i1 = e; }
        float m2 = -INFINITY;
#pragma unroll
        for (int e = 0; e < 8; e++) if (e != i1 && logit[e] > m2) m2 = logit[e];
#pragma unroll
        for (int e = 0; e < 8; e++) if (logit[e] >= m2) mbits |= 1u << e;
        sel[n] = (unsigned char)mbits;
    }
    // ballots (uniform control flow): half==1 waves contribute zero masks
#pragma unroll
    for (int e = 0; e < 8; e++) {
        const unsigned long long bal = __ballot((mbits >> e) & 1u);
        if (half == 0 && lane == 0) atomicAdd(&s_cnt[e], (int)__popcll(bal));
    }
    __syncthreads();
    if (t < 8) blkcnt[blockIdx.x * 8 + t] = s_cnt[t];
}

// ---------------- K1.5: single-block scan -> baseoff, counts, aux ----------------
__global__ __launch_bounds__(256) void scan_kernel(
    const int* __restrict__ blkcnt, int* __restrict__ baseoff,
    int* __restrict__ counts, float* __restrict__ out)
{
    __shared__ int s_tot[8];
    const int t = threadIdx.x;
    const int e = t >> 5;        // 8 experts x 32 lanes
    const int q = t & 31;
    const int b0 = q * (GBLK / 32);
    int partial = 0;
    for (int b = b0; b < b0 + GBLK / 32; b++) partial += blkcnt[b * 8 + e];
    int incl = partial;
#pragma unroll
    for (int d = 1; d < 32; d <<= 1) {
        const int v = __shfl_up(incl, d, 32);
        if (q >= d) incl += v;
    }
    const int excl = incl - partial;
    const int total = __shfl(incl, 31, 32);
    if (q == 0) { counts[e] = total; s_tot[e] = total; }
    int run = excl;
    for (int b = b0; b < b0 + GBLK / 32; b++) {
        baseoff[b * 8 + e] = run;
        run += blkcnt[b * 8 + e];
    }
    __syncthreads();
    if (t == 0) {
        double s = 0.0;
        for (int i = 0; i < 8; i++) { const double c = (double)s_tot[i]; s += c * c; }
        out[NPTS] = (float)(8.0 * s / ((double)NPTS * (double)NPTS));
    }
}

// ---------------- K2: scatter points into buckets (no atomics) ----------------
__global__ __launch_bounds__(128) void scatter_kernel(
    const unsigned char* __restrict__ sel, const int* __restrict__ baseoff,
    int* __restrict__ buckets)
{
    __shared__ int s_w0[8];
    const int t = threadIdx.x;
    const int n = blockIdx.x * 128 + t;
    const unsigned m = sel[n];
    const int w = t >> 6, lane = t & 63;
    unsigned long long bal[8];
#pragma unroll
    for (int e = 0; e < 8; e++) {
        bal[e] = __ballot((m >> e) & 1u);
        if (w == 0 && lane == 0) s_w0[e] = (int)__popcll(bal[e]);
    }
    __syncthreads();
#pragma unroll
    for (int e = 0; e < 8; e++) {
        if ((m >> e) & 1u) {
            int rank = (int)__popcll(bal[e] & ((1ull << lane) - 1ull));
            if (w == 1) rank += s_w0[e];
            buckets[e * NPTS + baseoff[blockIdx.x * 8 + e] + rank] = n;
        }
    }
}

// ---------------- K3: per-expert MFMA SIREN on gathered bucket entries ----------------
__global__ __launch_bounds__(256) void expert_kernel(
    const float* __restrict__ coords,
    const float* __restrict__ fw, const float* __restrict__ fb,
    const float* __restrict__ wl, const float* __restrict__ bl,
    const uint4* __restrict__ packA, const float* __restrict__ biasS,
    const int* __restrict__ counts, const int* __restrict__ buckets,
    float* __restrict__ out)
{
    const int e = blockIdx.x >> 11;            // CPE == 2048
    const int chunk = blockIdx.x & (CPE - 1);
    const int cnt = counts[e];
    const int base = chunk * 128;
    if (base >= cnt) return;

    __shared__ unsigned char s_ft[16 * 1024];
    __shared__ int s_id[128];
    __shared__ float s_b[192];
    __shared__ float s_wl[64];
    __shared__ float s_fw[192];
    __shared__ float s_fb[64];
    __shared__ float s_bl;

    const int t = threadIdx.x;
    if (t < 128) {
        const int gid = base + t;
        s_id[t] = (gid < cnt) ? buckets[e * NPTS + gid] : -1;
    }
    if (t < 192) {
        s_b[t] = biasS[e * 192 + t];
        s_fw[t] = fw[t];
    }
    if (t < 64) {
        s_fb[t] = fb[t];
        s_wl[t] = wl[e * 64 + t];
    }
    if (t == 0) s_bl = bl[e];
    __syncthreads();

    // ---- recompute features for 128 entries (2 threads per entry) ----
    const int half = t & 1;
    const int p = t >> 1;
    const int id_p = s_id[p];
    float fh[32];
    if (id_p >= 0) {
        const float c0 = coords[id_p * 3], c1 = coords[id_p * 3 + 1], c2 = coords[id_p * 3 + 2];
        if (half == 0) {
#pragma unroll
            for (int j = 0; j < 32; j++)
                fh[j] = s_fb[j] + c0 * s_fw[j * 3] + c1 * s_fw[j * 3 + 1] + c2 * s_fw[j * 3 + 2];
        } else {
#pragma unroll
            for (int j = 0; j < 32; j++) {
                const int row = j + 32;
                fh[j] = s_fb[row] + c0 * s_fw[row * 3] + c1 * s_fw[row * 3 + 1] + c2 * s_fw[row * 3 + 2];
            }
        }
    } else {
#pragma unroll
        for (int j = 0; j < 32; j++) fh[j] = 0.f;
    }
    {
        const int region = ((p >> 5) * 2 + ((p >> 4) & 1)) * 2 + half;   // (wv*2+nt)*2+ks
        const int slotc = p & 15;
#pragma unroll
        for (int g = 0; g < 4; g++) {
            uint4 q;
            q.x = pack2(fh[4 * g + 0], fh[4 * g + 1]);
            q.y = pack2(fh[4 * g + 2], fh[4 * g + 3]);
            q.z = pack2(fh[4 * g + 16], fh[4 * g + 17]);
            q.w = pack2(fh[4 * g + 18], fh[4 * g + 19]);
            *(uint4*)&s_ft[region * 1024 + (16 * g + slotc) * 16] = q;
        }
    }
    __syncthreads();

    // ---- MFMA phase: each wave handles 32 entries ----
    const int lane = t & 63;
    const int wv = t >> 6;
    const int g = lane >> 4, c = lane & 15;
    const int id0 = s_id[wv * 32 + c];
    const int id1 = s_id[wv * 32 + 16 + c];

    BFrag B0[2], B1[2];
#pragma unroll
    for (int ks = 0; ks < 2; ks++) {
        B0[ks].q = *(const uint4*)&s_ft[(((wv * 2 + 0) * 2 + ks) * 1024) + lane * 16];
        B1[ks].q = *(const uint4*)&s_ft[(((wv * 2 + 1) * 2 + ks) * 1024) + lane * 16];
    }

#pragma unroll 1
    for (int ell = 0; ell < 2; ell++) {
        f4v acc0[4], acc1[4];
#pragma unroll
        for (int tau = 0; tau < 4; tau++) {
            const float4 b = *(const float4*)&s_b[ell * 64 + tau * 16 + 4 * g];
            acc0[tau][0] = b.x; acc0[tau][1] = b.y; acc0[tau][2] = b.z; acc0[tau][3] = b.w;
            acc1[tau][0] = b.x; acc1[tau][1] = b.y; acc1[tau][2] = b.z; acc1[tau][3] = b.w;
        }
        const uint4* Ab = packA + (size_t)((e * 3 + ell) * 8) * 64 + lane;
#pragma unroll
        for (int tau = 0; tau < 4; tau++) {
            BFrag A0, A1;
            A0.q = Ab[(tau * 2 + 0) * 64];
            A1.q = Ab[(tau * 2 + 1) * 64];
            acc0[tau] = __builtin_amdgcn_mfma_f32_16x16x32_bf16(A0.s, B0[0].s, acc0[tau], 0, 0, 0);
            acc0[tau] = __builtin_amdgcn_mfma_f32_16x16x32_bf16(A1.s, B0[1].s, acc0[tau], 0, 0, 0);
            acc1[tau] = __builtin_amdgcn_mfma_f32_16x16x32_bf16(A0.s, B1[0].s, acc1[tau], 0, 0, 0);
            acc1[tau] = __builtin_amdgcn_mfma_f32_16x16x32_bf16(A1.s, B1[1].s, acc1[tau], 0, 0, 0);
        }
#pragma unroll
        for (int ks = 0; ks < 2; ks++) {
            B0[ks].u[0] = pack2(sinrev(acc0[2 * ks][0]), sinrev(acc0[2 * ks][1]));
            B0[ks].u[1] = pack2(sinrev(acc0[2 * ks][2]), sinrev(acc0[2 * ks][3]));
            B0[ks].u[2] = pack2(sinrev(acc0[2 * ks + 1][0]), sinrev(acc0[2 * ks + 1][1]));
            B0[ks].u[3] = pack2(sinrev(acc0[2 * ks + 1][2]), sinrev(acc0[2 * ks + 1][3]));
            B1[ks].u[0] = pack2(sinrev(acc1[2 * ks][0]), sinrev(acc1[2 * ks][1]));
            B1[ks].u[1] = pack2(sinrev(acc1[2 * ks][2]), sinrev(acc1[2 * ks][3]));
            B1[ks].u[2] = pack2(sinrev(acc1[2 * ks + 1][0]), sinrev(acc1[2 * ks + 1][1]));
            B1[ks].u[3] = pack2(sinrev(acc1[2 * ks + 1][2]), sinrev(acc1[2 * ks + 1][3]));
        }
    }

    // ---- layer 2 + final dot ----
    {
        f4v acc0[4], acc1[4];
#pragma unroll
        for (int tau = 0; tau < 4; tau++) {
            const float4 b = *(const float4*)&s_b[2 * 64 + tau * 16 + 4 * g];
            acc0[tau][0] = b.x; acc0[tau][1] = b.y; acc0[tau][2] = b.z; acc0[tau][3] = b.w;
            acc1[tau][0] = b.x; acc1[tau][1] = b.y; acc1[tau][2] = b.z; acc1[tau][3] = b.w;
        }
        const uint4* Ab = packA + (size_t)((e * 3 + 2) * 8) * 64 + lane;
#pragma unroll
        for (int tau = 0; tau < 4; tau++) {
            BFrag A0, A1;
            A0.q = Ab[(tau * 2 + 0) * 64];
            A1.q = Ab[(tau * 2 + 1) * 64];
            acc0[tau] = __builtin_amdgcn_mfma_f32_16x16x32_bf16(A0.s, B0[0].s, acc0[tau], 0, 0, 0);
            acc0[tau] = __builtin_amdgcn_mfma_f32_16x16x32_bf16(A1.s, B0[1].s, acc0[tau], 0, 0, 0);
            acc1[tau] = __builtin_amdgcn_mfma_f32_16x16x32_bf16(A0.s, B1[0].s, acc1[tau], 0, 0, 0);
            acc1[tau] = __builtin_amdgcn_mfma_f32_16x16x32_bf16(A1.s, B1[1].s, acc1[tau], 0, 0, 0);
        }
        float px0 = 0.f, px1 = 0.f;
#pragma unroll
        for (int tau = 0; tau < 4; tau++) {
            const float4 w = *(const float4*)&s_wl[tau * 16 + 4 * g];
            px0 += sinrev(acc0[tau][0]) * w.x + sinrev(acc0[tau][1]) * w.y
                 + sinrev(acc0[tau][2]) * w.z + sinrev(acc0[tau][3]) * w.w;
            px1 += sinrev(acc1[tau][0]) * w.x + sinrev(acc1[tau][1]) * w.y
                 + sinrev(acc1[tau][2]) * w.z + sinrev(acc1[tau][3]) * w.w;
        }
        px0 += __shfl_xor(px0, 16, 64); px0 += __shfl_xor(px0, 32, 64);
        px1 += __shfl_xor(px1, 16, 64); px1 += __shfl_xor(px1, 32, 64);
        if (g == 0) {
            if (id0 >= 0) atomicAdd(&out[id0], px0 + s_bl);
            if (id1 >= 0) atomicAdd(&out[id1], px1 + s_bl);
        }
    }
}

extern "C" void kernel_launch(void* const* d_in, const int* in_sizes, int n_in,
                              void* d_out, int out_size, void* d_ws, size_t ws_size,
                              hipStream_t stream)
{
    const float* coords = (const float*)d_in[0];
    const float* fw  = (const float*)d_in[1];
    const float* fb  = (const float*)d_in[2];
    const float* gw1 = (const float*)d_in[3];
    const float* gb1 = (const float*)d_in[4];
    const float* lng = (const float*)d_in[5];
    const float* lnb = (const float*)d_in[6];
    const float* gw2 = (const float*)d_in[7];
    const float* gb2 = (const float*)d_in[8];
    const float* we0 = (const float*)d_in[9];
    const float* be0 = (const float*)d_in[10];
    const float* wm  = (const float*)d_in[11];
    const float* bm  = (const float*)d_in[12];
    const float* wl  = (const float*)d_in[13];
    const float* bl  = (const float*)d_in[14];
    float* out = (float*)d_out;

    char* ws = (char*)d_ws;
    int* counts           = (int*)ws;                        // 64 B
    int* buckets          = (int*)(ws + 64);                 // 8*NPTS*4 = 8388608
    uint4* packA          = (uint4*)(ws + 8388672);          // 196608
    float* biasS          = (float*)(ws + 8585280);          // 6144
    int* blkcnt           = (int*)(ws + 8591424);            // GBLK*8*4 = 65536
    int* baseoff          = (int*)(ws + 8656960);            // 65536
    unsigned char* sel    = (unsigned char*)(ws + 8722496);  // NPTS = 262144

    hipMemsetAsync(d_out, 0, (size_t)(NPTS + 1) * sizeof(float), stream);

    prep_kernel<<<54, 256, 0, stream>>>(we0, be0, wm, bm, packA, biasS);
    gate_kernel<<<GBLK, 256, 0, stream>>>(coords, fw, fb, gw1, gb1, lng, lnb, gw2, gb2,
                                          sel, blkcnt);
    scan_kernel<<<1, 256, 0, stream>>>(blkcnt, baseoff, counts, out);
    scatter_kernel<<<GBLK, 128, 0, stream>>>(sel, baseoff, buckets);
    expert_kernel<<<8 * CPE, 256, 0, stream>>>(coords, fw, fb, wl, bl, packA, biasS,
                                               counts, buckets, out);
}

// Round 7
// 146.234 us; speedup vs baseline: 1.5018x; 1.5018x over previous
//
#include <hip/hip_runtime.h>
#include <math.h>

#define NPTS 262144
#define GBLK (NPTS / 128)     // 2048 gate blocks (128 points each)
#define CPE  2048             // chunks per expert in expert grid
#define TAU  0.005f           // refine margin threshold (logit units)

typedef float f4v __attribute__((ext_vector_type(4)));
typedef short s8v __attribute__((ext_vector_type(8)));

static __device__ __forceinline__ unsigned short f2bf(float f) {
    unsigned u = __float_as_uint(f);
    u += 0x7fffu + ((u >> 16) & 1u);
    return (unsigned short)(u >> 16);
}
static __device__ __forceinline__ float bf2f(unsigned short h) {
    return __uint_as_float(((unsigned)h) << 16);
}
static __device__ __forceinline__ unsigned pack2(float lo, float hi) {
    return ((unsigned)f2bf(hi) << 16) | (unsigned)f2bf(lo);
}
static __device__ __forceinline__ unsigned pk2b(unsigned short lo, unsigned short hi) {
    return ((unsigned)hi << 16) | (unsigned)lo;
}
static __device__ __forceinline__ float sinrev(float x) {   // sin(2*pi*x)
    return __builtin_amdgcn_sinf(x);
}

union BFrag { uint4 q; unsigned u[4]; s8v s; };

// ---------------- prep: pack expert A-frags + scaled biases + gate hi/lo packs ----------------
__global__ __launch_bounds__(256) void prep_kernel(
    const float* __restrict__ we0, const float* __restrict__ be0,
    const float* __restrict__ wm, const float* __restrict__ bm,
    const float* __restrict__ gw1, const float* __restrict__ gw2,
    uint4* __restrict__ packA, float* __restrict__ biasS,
    uint4* __restrict__ packGW1H, uint4* __restrict__ packGW1L,
    uint4* __restrict__ packGW2H, uint4* __restrict__ packGW2L)
{
    const int idx = blockIdx.x * 256 + threadIdx.x;
    const float PI2I = 0.15915494309189535f;
    if (idx < 12288) {
        const int l = idx & 63;
        const int fr = (idx >> 6) & 7;
        const int grp = idx >> 9;            // e*3 + ell
        const int e = grp / 3, ell = grp % 3;
        const int tau = fr >> 1, ks = fr & 1;
        const int g = l >> 4, m = l & 15;
        const int row = tau * 16 + m;
        const float scale = (ell == 0) ? (22.5f + 45.0f * (float)e) * PI2I : 30.0f * PI2I;
        const float* W = (ell == 0) ? (we0 + e * 4096) : (wm + ((ell - 1) * 8 + e) * 4096);
        unsigned short v[8];
#pragma unroll
        for (int i = 0; i < 8; i++) {
            const int k = 32 * ks + 4 * g + (i < 4 ? i : i + 12);
            v[i] = f2bf(W[row * 64 + k] * scale);
        }
        uint4 q;
        q.x = pk2b(v[0], v[1]); q.y = pk2b(v[2], v[3]);
        q.z = pk2b(v[4], v[5]); q.w = pk2b(v[6], v[7]);
        packA[idx] = q;
    } else if (idx < 13824) {
        const int j = idx - 12288;           // e*192 + ell*64 + r
        const int r = j & 63;
        const int grp = j >> 6;
        const int e = grp / 3, ell = grp % 3;
        const float scale = (ell == 0) ? (22.5f + 45.0f * (float)e) * PI2I : 30.0f * PI2I;
        const float b = (ell == 0) ? be0[e * 64 + r] : bm[((ell - 1) * 8 + e) * 64 + r];
        biasS[j] = b * scale;
    } else if (idx < 14336) {
        // gate gw1 hi/lo A-frags: 8 frags (tau*2+ks) x 64 lanes
        const int j = idx - 13824;           // 0..511
        const int l = j & 63;
        const int fr = j >> 6;
        const int tau = fr >> 1, ks = fr & 1;
        const int g = l >> 4;
        const int row = tau * 16 + (l & 15);
        unsigned short vh[8], vl[8];
#pragma unroll
        for (int i = 0; i < 8; i++) {
            const int k = 32 * ks + 4 * g + (i < 4 ? i : i + 12);
            const float x = gw1[row * 64 + k];
            const unsigned short h = f2bf(x);
            vh[i] = h;
            vl[i] = f2bf(x - bf2f(h));
        }
        uint4 qh, ql;
        qh.x = pk2b(vh[0], vh[1]); qh.y = pk2b(vh[2], vh[3]);
        qh.z = pk2b(vh[4], vh[5]); qh.w = pk2b(vh[6], vh[7]);
        ql.x = pk2b(vl[0], vl[1]); ql.y = pk2b(vl[2], vl[3]);
        ql.z = pk2b(vl[4], vl[5]); ql.w = pk2b(vl[6], vl[7]);
        packGW1H[j] = qh; packGW1L[j] = ql;
    } else if (idx < 14464) {
        // gate gw2 hi/lo A-frags: rows 0..7 = gw2, rows 8..15 = 0; 2 frags (ks) x 64 lanes
        const int j = idx - 14336;           // 0..127
        const int l = j & 63;
        const int ks = j >> 6;
        const int g = l >> 4;
        const int row = l & 15;
        unsigned short vh[8], vl[8];
#pragma unroll
        for (int i = 0; i < 8; i++) {
            const int k = 32 * ks + 4 * g + (i < 4 ? i : i + 12);
            const float x = (row < 8) ? gw2[row * 64 + k] : 0.f;
            const unsigned short h = f2bf(x);
            vh[i] = h;
            vl[i] = f2bf(x - bf2f(h));
        }
        uint4 qh, ql;
        qh.x = pk2b(vh[0], vh[1]); qh.y = pk2b(vh[2], vh[3]);
        qh.z = pk2b(vh[4], vh[5]); qh.w = pk2b(vh[6], vh[7]);
        ql.x = pk2b(vl[0], vl[1]); ql.y = pk2b(vl[2], vl[3]);
        ql.z = pk2b(vl[4], vl[5]); ql.w = pk2b(vl[6], vl[7]);
        packGW2H[j] = qh; packGW2L[j] = ql;
    }
}

// ---------------- K1: gate via MFMA (hi/lo split) + margin flag for refine ----------------
// 512 threads = 8 waves x 16 points = 128 points per block.
__global__ __launch_bounds__(512) void gate_kernel(
    const float* __restrict__ coords,
    const float* __restrict__ fw, const float* __restrict__ fb,
    const float* __restrict__ gb1, const float* __restrict__ lng,
    const float* __restrict__ lnb, const float* __restrict__ gb2,
    const uint4* __restrict__ packGW1H, const uint4* __restrict__ packGW1L,
    const uint4* __restrict__ packGW2H, const uint4* __restrict__ packGW2L,
    unsigned char* __restrict__ sel, int* __restrict__ blkcnt,
    int* __restrict__ reflist, int* __restrict__ refcnt)
{
    __shared__ float s_fw[192], s_fb[64], s_gb1[64], s_lng[64], s_lnb[64], s_gb2[8];
    __shared__ int s_cnt[8];
    const int t = threadIdx.x;
    if (t < 192) s_fw[t] = fw[t];
    if (t < 64) { s_fb[t] = fb[t]; s_gb1[t] = gb1[t]; s_lng[t] = lng[t]; s_lnb[t] = lnb[t]; }
    if (t < 8) { s_gb2[t] = gb2[t]; s_cnt[t] = 0; }
    __syncthreads();

    const int lane = t & 63;
    const int wv = t >> 6;
    const int g = lane >> 4, c = lane & 15;
    const int n = blockIdx.x * 128 + wv * 16 + c;

    // ---- features: this lane's 16 k-values of point n (fp32, exact order) ----
    const float c0 = coords[n * 3], c1 = coords[n * 3 + 1], c2 = coords[n * 3 + 2];
    float fv[16];
#pragma unroll
    for (int s = 0; s < 4; s++) {
#pragma unroll
        for (int j = 0; j < 4; j++) {
            const int k = 16 * s + 4 * g + j;
            fv[s * 4 + j] = s_fb[k] + c0 * s_fw[k * 3] + c1 * s_fw[k * 3 + 1] + c2 * s_fw[k * 3 + 2];
        }
    }
    unsigned short fh[16]; float fl[16];
#pragma unroll
    for (int i = 0; i < 16; i++) {
        fh[i] = f2bf(fv[i]);
        fl[i] = fv[i] - bf2f(fh[i]);
    }
    BFrag Bh[2], Bl[2];
#pragma unroll
    for (int ks = 0; ks < 2; ks++) {
#pragma unroll
        for (int q = 0; q < 4; q++) {
            Bh[ks].u[q] = pk2b(fh[ks * 8 + 2 * q], fh[ks * 8 + 2 * q + 1]);
            Bl[ks].u[q] = pack2(fl[ks * 8 + 2 * q], fl[ks * 8 + 2 * q + 1]);
        }
    }

    // ---- g = gw1 @ f + gb1 via 3-term MFMA ----
    f4v acc[4];
#pragma unroll
    for (int tau = 0; tau < 4; tau++) {
        const float4 b = *(const float4*)&s_gb1[tau * 16 + 4 * g];
        acc[tau][0] = b.x; acc[tau][1] = b.y; acc[tau][2] = b.z; acc[tau][3] = b.w;
    }
#pragma unroll
    for (int tau = 0; tau < 4; tau++) {
        BFrag AH0, AH1, AL0, AL1;
        AH0.q = packGW1H[(tau * 2 + 0) * 64 + lane];
        AH1.q = packGW1H[(tau * 2 + 1) * 64 + lane];
        AL0.q = packGW1L[(tau * 2 + 0) * 64 + lane];
        AL1.q = packGW1L[(tau * 2 + 1) * 64 + lane];
        acc[tau] = __builtin_amdgcn_mfma_f32_16x16x32_bf16(AH0.s, Bh[0].s, acc[tau], 0, 0, 0);
        acc[tau] = __builtin_amdgcn_mfma_f32_16x16x32_bf16(AH1.s, Bh[1].s, acc[tau], 0, 0, 0);
        acc[tau] = __builtin_amdgcn_mfma_f32_16x16x32_bf16(AH0.s, Bl[0].s, acc[tau], 0, 0, 0);
        acc[tau] = __builtin_amdgcn_mfma_f32_16x16x32_bf16(AH1.s, Bl[1].s, acc[tau], 0, 0, 0);
        acc[tau] = __builtin_amdgcn_mfma_f32_16x16x32_bf16(AL0.s, Bh[0].s, acc[tau], 0, 0, 0);
        acc[tau] = __builtin_amdgcn_mfma_f32_16x16x32_bf16(AL1.s, Bh[1].s, acc[tau], 0, 0, 0);
    }

    // ---- LayerNorm over the 64 rows (cross-lane over g groups) ----
    float s1 = 0.f;
#pragma unroll
    for (int tau = 0; tau < 4; tau++)
#pragma unroll
        for (int j = 0; j < 4; j++) s1 += acc[tau][j];
    s1 += __shfl_xor(s1, 16, 64); s1 += __shfl_xor(s1, 32, 64);
    const float mu = s1 * (1.f / 64.f);
    float s2 = 0.f;
#pragma unroll
    for (int tau = 0; tau < 4; tau++)
#pragma unroll
        for (int j = 0; j < 4; j++) { const float d = acc[tau][j] - mu; s2 += d * d; }
    s2 += __shfl_xor(s2, 16, 64); s2 += __shfl_xor(s2, 32, 64);
    const float rs = rsqrtf(s2 * (1.f / 64.f) + 1e-5f);

    float gn[16];
#pragma unroll
    for (int tau = 0; tau < 4; tau++) {
        const float4 lg = *(const float4*)&s_lng[tau * 16 + 4 * g];
        const float4 lb = *(const float4*)&s_lnb[tau * 16 + 4 * g];
        gn[tau * 4 + 0] = (acc[tau][0] - mu) * rs * lg.x + lb.x;
        gn[tau * 4 + 1] = (acc[tau][1] - mu) * rs * lg.y + lb.y;
        gn[tau * 4 + 2] = (acc[tau][2] - mu) * rs * lg.z + lb.z;
        gn[tau * 4 + 3] = (acc[tau][3] - mu) * rs * lg.w + lb.w;
    }
    // D->B repack of gn (proven mapping) with hi/lo split
    unsigned short gh[16]; float gl[16];
#pragma unroll
    for (int i = 0; i < 16; i++) { gh[i] = f2bf(gn[i]); gl[i] = gn[i] - bf2f(gh[i]); }
    BFrag Gh[2], Gl[2];
#pragma unroll
    for (int ks = 0; ks < 2; ks++) {
        Gh[ks].u[0] = pk2b(gh[(2 * ks) * 4 + 0], gh[(2 * ks) * 4 + 1]);
        Gh[ks].u[1] = pk2b(gh[(2 * ks) * 4 + 2], gh[(2 * ks) * 4 + 3]);
        Gh[ks].u[2] = pk2b(gh[(2 * ks + 1) * 4 + 0], gh[(2 * ks + 1) * 4 + 1]);
        Gh[ks].u[3] = pk2b(gh[(2 * ks + 1) * 4 + 2], gh[(2 * ks + 1) * 4 + 3]);
        Gl[ks].u[0] = pack2(gl[(2 * ks) * 4 + 0], gl[(2 * ks) * 4 + 1]);
        Gl[ks].u[1] = pack2(gl[(2 * ks) * 4 + 2], gl[(2 * ks) * 4 + 3]);
        Gl[ks].u[2] = pack2(gl[(2 * ks + 1) * 4 + 0], gl[(2 * ks + 1) * 4 + 1]);
        Gl[ks].u[3] = pack2(gl[(2 * ks + 1) * 4 + 2], gl[(2 * ks + 1) * 4 + 3]);
    }

    // ---- logits = gw2 @ gn via 3-term MFMA (rows 0..7 valid) ----
    f4v lacc = {0.f, 0.f, 0.f, 0.f};
    BFrag W0, W1, V0, V1;
    W0.q = packGW2H[0 * 64 + lane]; W1.q = packGW2H[1 * 64 + lane];
    V0.q = packGW2L[0 * 64 + lane]; V1.q = packGW2L[1 * 64 + lane];
    lacc = __builtin_amdgcn_mfma_f32_16x16x32_bf16(W0.s, Gh[0].s, lacc, 0, 0, 0);
    lacc = __builtin_amdgcn_mfma_f32_16x16x32_bf16(W1.s, Gh[1].s, lacc, 0, 0, 0);
    lacc = __builtin_amdgcn_mfma_f32_16x16x32_bf16(W0.s, Gl[0].s, lacc, 0, 0, 0);
    lacc = __builtin_amdgcn_mfma_f32_16x16x32_bf16(W1.s, Gl[1].s, lacc, 0, 0, 0);
    lacc = __builtin_amdgcn_mfma_f32_16x16x32_bf16(V0.s, Gh[0].s, lacc, 0, 0, 0);
    lacc = __builtin_amdgcn_mfma_f32_16x16x32_bf16(V1.s, Gh[1].s, lacc, 0, 0, 0);

    float other[4];
#pragma unroll
    for (int j = 0; j < 4; j++) other[j] = __shfl_xor(lacc[j], 16, 64);
    float logit[8];
#pragma unroll
    for (int j = 0; j < 4; j++) {
        logit[j] = lacc[j] + s_gb2[j];          // valid on g==0 lanes (rows 0..3)
        logit[4 + j] = other[j] + s_gb2[4 + j]; // rows 4..7 from g==1 partner
    }

    // ---- top-2 (>= 2nd-largest semantics) + margin flag ----
    float m1 = logit[0]; int i1 = 0;
#pragma unroll
    for (int e = 1; e < 8; e++) if (logit[e] > m1) { m1 = logit[e]; i1 = e; }
    float m2 = -INFINITY; int i2 = -1;
#pragma unroll
    for (int e = 0; e < 8; e++) if (e != i1 && logit[e] > m2) { m2 = logit[e]; i2 = e; }
    float m3 = -INFINITY;
#pragma unroll
    for (int e = 0; e < 8; e++) if (e != i1 && e != i2 && logit[e] > m3) m3 = logit[e];
    unsigned mbits = 0;
#pragma unroll
    for (int e = 0; e < 8; e++) if (logit[e] >= m2) mbits |= 1u << e;

    const bool active = (g == 0);
    if (active) sel[n] = (unsigned char)mbits;
    const bool flg = active && (m2 - m3 < TAU);

#pragma unroll
    for (int e = 0; e < 8; e++) {
        const unsigned long long bal = __ballot(active && ((mbits >> e) & 1u));
        if (lane == 0) atomicAdd(&s_cnt[e], (int)__popcll(bal));
    }
    {
        const unsigned long long bal = __ballot(flg);
        int pos0 = 0;
        if (lane == 0 && bal) pos0 = atomicAdd(refcnt, (int)__popcll(bal));
        pos0 = __shfl(pos0, 0, 64);
        if (flg) {
            const int rank = (int)__popcll(bal & ((1ull << lane) - 1ull));
            reflist[pos0 + rank] = n;
        }
    }
    __syncthreads();
    if (t < 8) blkcnt[blockIdx.x * 8 + t] = s_cnt[t];
}

// ---------------- K1.25: exact-fp32 refine of flagged points ----------------
__global__ __launch_bounds__(256) void refine_kernel(
    const float* __restrict__ coords,
    const float* __restrict__ fw, const float* __restrict__ fb,
    const float* __restrict__ gw1, const float* __restrict__ gb1,
    const float* __restrict__ lng, const float* __restrict__ lnb,
    const float* __restrict__ gw2, const float* __restrict__ gb2,
    const int* __restrict__ reflist, const int* __restrict__ refcnt,
    unsigned char* __restrict__ sel, int* __restrict__ blkcnt)
{
    __shared__ float s_gw1[4096];
    __shared__ float s_gw2[512];
    __shared__ float s_fw[192], s_fb[64], s_gb1[64], s_lng[64], s_lnb[64], s_gb2[8];
    const int t = threadIdx.x;
    for (int i = t; i < 4096; i += 256) s_gw1[i] = gw1[i];
    for (int i = t; i < 512; i += 256) s_gw2[i] = gw2[i];
    if (t < 192) s_fw[t] = fw[t];
    if (t < 64) { s_fb[t] = fb[t]; s_gb1[t] = gb1[t]; s_lng[t] = lng[t]; s_lnb[t] = lnb[t]; }
    if (t < 8) s_gb2[t] = gb2[t];
    __syncthreads();

    const int R = *refcnt;
    for (int idx = blockIdx.x * 256 + t; idx < R; idx += gridDim.x * 256) {
        const int n = reflist[idx];
        const float c0 = coords[n * 3], c1 = coords[n * 3 + 1], c2 = coords[n * 3 + 2];
        float f[64];
#pragma unroll
        for (int j = 0; j < 64; j++)
            f[j] = s_fb[j] + c0 * s_fw[j * 3] + c1 * s_fw[j * 3 + 1] + c2 * s_fw[j * 3 + 2];
        float gg[64];
        float mu = 0.f;
#pragma unroll 4
        for (int row = 0; row < 64; row++) {
            float a = s_gb1[row];
#pragma unroll
            for (int k = 0; k < 64; k += 4) {
                const float4 w = *(const float4*)&s_gw1[row * 64 + k];
                a += f[k] * w.x + f[k + 1] * w.y + f[k + 2] * w.z + f[k + 3] * w.w;
            }
            gg[row] = a; mu += a;
        }
        mu *= (1.f / 64.f);
        float var = 0.f;
#pragma unroll
        for (int row = 0; row < 64; row++) { const float d = gg[row] - mu; var += d * d; }
        const float rs = rsqrtf(var * (1.f / 64.f) + 1e-5f);
        float logit[8];
#pragma unroll
        for (int e = 0; e < 8; e++) logit[e] = s_gb2[e];
#pragma unroll 4
        for (int row = 0; row < 64; row++) {
            const float gn = (gg[row] - mu) * rs * s_lng[row] + s_lnb[row];
#pragma unroll
            for (int e = 0; e < 8; e++) logit[e] += gn * s_gw2[e * 64 + row];
        }
        float m1 = logit[0]; int i1 = 0;
#pragma unroll
        for (int e = 1; e < 8; e++) if (logit[e] > m1) { m1 = logit[e]; i1 = e; }
        float m2 = -INFINITY;
#pragma unroll
        for (int e = 0; e < 8; e++) if (e != i1 && logit[e] > m2) m2 = logit[e];
        unsigned mbits = 0;
#pragma unroll
        for (int e = 0; e < 8; e++) if (logit[e] >= m2) mbits |= 1u << e;

        const unsigned old = sel[n];
        if (mbits != old) {
            sel[n] = (unsigned char)mbits;
            const int b = n >> 7;
#pragma unroll
            for (int e = 0; e < 8; e++) {
                const int was = (old >> e) & 1, now = (mbits >> e) & 1;
                if (was != now) atomicAdd(&blkcnt[b * 8 + e], now - was);
            }
        }
    }
}

// ---------------- K1.5: single-block scan -> baseoff, counts, aux ----------------
__global__ __launch_bounds__(256) void scan_kernel(
    const int* __restrict__ blkcnt, int* __restrict__ baseoff,
    int* __restrict__ counts, float* __restrict__ out)
{
    __shared__ int s_tot[8];
    const int t = threadIdx.x;
    const int e = t >> 5;        // 8 experts x 32 lanes
    const int q = t & 31;
    const int b0 = q * (GBLK / 32);
    int partial = 0;
    for (int b = b0; b < b0 + GBLK / 32; b++) partial += blkcnt[b * 8 + e];
    int incl = partial;
#pragma unroll
    for (int d = 1; d < 32; d <<= 1) {
        const int v = __shfl_up(incl, d, 32);
        if (q >= d) incl += v;
    }
    const int excl = incl - partial;
    const int total = __shfl(incl, 31, 32);
    if (q == 0) { counts[e] = total; s_tot[e] = total; }
    int run = excl;
    for (int b = b0; b < b0 + GBLK / 32; b++) {
        baseoff[b * 8 + e] = run;
        run += blkcnt[b * 8 + e];
    }
    __syncthreads();
    if (t == 0) {
        double s = 0.0;
        for (int i = 0; i < 8; i++) { const double c = (double)s_tot[i]; s += c * c; }
        out[NPTS] = (float)(8.0 * s / ((double)NPTS * (double)NPTS));
    }
}

// ---------------- K2: scatter points into buckets (no atomics) ----------------
__global__ __launch_bounds__(128) void scatter_kernel(
    const unsigned char* __restrict__ sel, const int* __restrict__ baseoff,
    int* __restrict__ buckets)
{
    __shared__ int s_w0[8];
    const int t = threadIdx.x;
    const int n = blockIdx.x * 128 + t;
    const unsigned m = sel[n];
    const int w = t >> 6, lane = t & 63;
    unsigned long long bal[8];
#pragma unroll
    for (int e = 0; e < 8; e++) {
        bal[e] = __ballot((m >> e) & 1u);
        if (w == 0 && lane == 0) s_w0[e] = (int)__popcll(bal[e]);
    }
    __syncthreads();
#pragma unroll
    for (int e = 0; e < 8; e++) {
        if ((m >> e) & 1u) {
            int rank = (int)__popcll(bal[e] & ((1ull << lane) - 1ull));
            if (w == 1) rank += s_w0[e];
            buckets[e * NPTS + baseoff[blockIdx.x * 8 + e] + rank] = n;
        }
    }
}

// ---------------- K3: per-expert MFMA SIREN on gathered bucket entries ----------------
__global__ __launch_bounds__(256) void expert_kernel(
    const float* __restrict__ coords,
    const float* __restrict__ fw, const float* __restrict__ fb,
    const float* __restrict__ wl, const float* __restrict__ bl,
    const uint4* __restrict__ packA, const float* __restrict__ biasS,
    const int* __restrict__ counts, const int* __restrict__ buckets,
    float* __restrict__ out)
{
    const int e = blockIdx.x >> 11;            // CPE == 2048
    const int chunk = blockIdx.x & (CPE - 1);
    const int cnt = counts[e];
    const int base = chunk * 128;
    if (base >= cnt) return;

    __shared__ unsigned char s_ft[16 * 1024];
    __shared__ int s_id[128];
    __shared__ float s_b[192];
    __shared__ float s_wl[64];
    __shared__ float s_fw[192];
    __shared__ float s_fb[64];
    __shared__ float s_bl;

    const int t = threadIdx.x;
    if (t < 128) {
        const int gid = base + t;
        s_id[t] = (gid < cnt) ? buckets[e * NPTS + gid] : -1;
    }
    if (t < 192) {
        s_b[t] = biasS[e * 192 + t];
        s_fw[t] = fw[t];
    }
    if (t < 64) {
        s_fb[t] = fb[t];
        s_wl[t] = wl[e * 64 + t];
    }
    if (t == 0) s_bl = bl[e];
    __syncthreads();

    const int half = t & 1;
    const int p = t >> 1;
    const int id_p = s_id[p];
    float fh[32];
    if (id_p >= 0) {
        const float c0 = coords[id_p * 3], c1 = coords[id_p * 3 + 1], c2 = coords[id_p * 3 + 2];
        if (half == 0) {
#pragma unroll
            for (int j = 0; j < 32; j++)
                fh[j] = s_fb[j] + c0 * s_fw[j * 3] + c1 * s_fw[j * 3 + 1] + c2 * s_fw[j * 3 + 2];
        } else {
#pragma unroll
            for (int j = 0; j < 32; j++) {
                const int row = j + 32;
                fh[j] = s_fb[row] + c0 * s_fw[row * 3] + c1 * s_fw[row * 3 + 1] + c2 * s_fw[row * 3 + 2];
            }
        }
    } else {
#pragma unroll
        for (int j = 0; j < 32; j++) fh[j] = 0.f;
    }
    {
        const int region = ((p >> 5) * 2 + ((p >> 4) & 1)) * 2 + half;
        const int slotc = p & 15;
#pragma unroll
        for (int g = 0; g < 4; g++) {
            uint4 q;
            q.x = pack2(fh[4 * g + 0], fh[4 * g + 1]);
            q.y = pack2(fh[4 * g + 2], fh[4 * g + 3]);
            q.z = pack2(fh[4 * g + 16], fh[4 * g + 17]);
            q.w = pack2(fh[4 * g + 18], fh[4 * g + 19]);
            *(uint4*)&s_ft[region * 1024 + (16 * g + slotc) * 16] = q;
        }
    }
    __syncthreads();

    const int lane = t & 63;
    const int wv = t >> 6;
    const int g = lane >> 4, c = lane & 15;
    const int id0 = s_id[wv * 32 + c];
    const int id1 = s_id[wv * 32 + 16 + c];

    BFrag B0[2], B1[2];
#pragma unroll
    for (int ks = 0; ks < 2; ks++) {
        B0[ks].q = *(const uint4*)&s_ft[(((wv * 2 + 0) * 2 + ks) * 1024) + lane * 16];
        B1[ks].q = *(const uint4*)&s_ft[(((wv * 2 + 1) * 2 + ks) * 1024) + lane * 16];
    }

#pragma unroll 1
    for (int ell = 0; ell < 2; ell++) {
        f4v acc0[4], acc1[4];
#pragma unroll
        for (int tau = 0; tau < 4; tau++) {
            const float4 b = *(const float4*)&s_b[ell * 64 + tau * 16 + 4 * g];
            acc0[tau][0] = b.x; acc0[tau][1] = b.y; acc0[tau][2] = b.z; acc0[tau][3] = b.w;
            acc1[tau][0] = b.x; acc1[tau][1] = b.y; acc1[tau][2] = b.z; acc1[tau][3] = b.w;
        }
        const uint4* Ab = packA + (size_t)((e * 3 + ell) * 8) * 64 + lane;
#pragma unroll
        for (int tau = 0; tau < 4; tau++) {
            BFrag A0, A1;
            A0.q = Ab[(tau * 2 + 0) * 64];
            A1.q = Ab[(tau * 2 + 1) * 64];
            acc0[tau] = __builtin_amdgcn_mfma_f32_16x16x32_bf16(A0.s, B0[0].s, acc0[tau], 0, 0, 0);
            acc0[tau] = __builtin_amdgcn_mfma_f32_16x16x32_bf16(A1.s, B0[1].s, acc0[tau], 0, 0, 0);
            acc1[tau] = __builtin_amdgcn_mfma_f32_16x16x32_bf16(A0.s, B1[0].s, acc1[tau], 0, 0, 0);
            acc1[tau] = __builtin_amdgcn_mfma_f32_16x16x32_bf16(A1.s, B1[1].s, acc1[tau], 0, 0, 0);
        }
#pragma unroll
        for (int ks = 0; ks < 2; ks++) {
            B0[ks].u[0] = pack2(sinrev(acc0[2 * ks][0]), sinrev(acc0[2 * ks][1]));
            B0[ks].u[1] = pack2(sinrev(acc0[2 * ks][2]), sinrev(acc0[2 * ks][3]));
            B0[ks].u[2] = pack2(sinrev(acc0[2 * ks + 1][0]), sinrev(acc0[2 * ks + 1][1]));
            B0[ks].u[3] = pack2(sinrev(acc0[2 * ks + 1][2]), sinrev(acc0[2 * ks + 1][3]));
            B1[ks].u[0] = pack2(sinrev(acc1[2 * ks][0]), sinrev(acc1[2 * ks][1]));
            B1[ks].u[1] = pack2(sinrev(acc1[2 * ks][2]), sinrev(acc1[2 * ks][3]));
            B1[ks].u[2] = pack2(sinrev(acc1[2 * ks + 1][0]), sinrev(acc1[2 * ks + 1][1]));
            B1[ks].u[3] = pack2(sinrev(acc1[2 * ks + 1][2]), sinrev(acc1[2 * ks + 1][3]));
        }
    }

    {
        f4v acc0[4], acc1[4];
#pragma unroll
        for (int tau = 0; tau < 4; tau++) {
            const float4 b = *(const float4*)&s_b[2 * 64 + tau * 16 + 4 * g];
            acc0[tau][0] = b.x; acc0[tau][1] = b.y; acc0[tau][2] = b.z; acc0[tau][3] = b.w;
            acc1[tau][0] = b.x; acc1[tau][1] = b.y; acc1[tau][2] = b.z; acc1[tau][3] = b.w;
        }
        const uint4* Ab = packA + (size_t)((e * 3 + 2) * 8) * 64 + lane;
#pragma unroll
        for (int tau = 0; tau < 4; tau++) {
            BFrag A0, A1;
            A0.q = Ab[(tau * 2 + 0) * 64];
            A1.q = Ab[(tau * 2 + 1) * 64];
            acc0[tau] = __builtin_amdgcn_mfma_f32_16x16x32_bf16(A0.s, B0[0].s, acc0[tau], 0, 0, 0);
            acc0[tau] = __builtin_amdgcn_mfma_f32_16x16x32_bf16(A1.s, B0[1].s, acc0[tau], 0, 0, 0);
            acc1[tau] = __builtin_amdgcn_mfma_f32_16x16x32_bf16(A0.s, B1[0].s, acc1[tau], 0, 0, 0);
            acc1[tau] = __builtin_amdgcn_mfma_f32_16x16x32_bf16(A1.s, B1[1].s, acc1[tau], 0, 0, 0);
        }
        float px0 = 0.f, px1 = 0.f;
#pragma unroll
        for (int tau = 0; tau < 4; tau++) {
            const float4 w = *(const float4*)&s_wl[tau * 16 + 4 * g];
            px0 += sinrev(acc0[tau][0]) * w.x + sinrev(acc0[tau][1]) * w.y
                 + sinrev(acc0[tau][2]) * w.z + sinrev(acc0[tau][3]) * w.w;
            px1 += sinrev(acc1[tau][0]) * w.x + sinrev(acc1[tau][1]) * w.y
                 + sinrev(acc1[tau][2]) * w.z + sinrev(acc1[tau][3]) * w.w;
        }
        px0 += __shfl_xor(px0, 16, 64); px0 += __shfl_xor(px0, 32, 64);
        px1 += __shfl_xor(px1, 16, 64); px1 += __shfl_xor(px1, 32, 64);
        if (g == 0) {
            if (id0 >= 0) atomicAdd(&out[id0], px0 + s_bl);
            if (id1 >= 0) atomicAdd(&out[id1], px1 + s_bl);
        }
    }
}

extern "C" void kernel_launch(void* const* d_in, const int* in_sizes, int n_in,
                              void* d_out, int out_size, void* d_ws, size_t ws_size,
                              hipStream_t stream)
{
    const float* coords = (const float*)d_in[0];
    const float* fw  = (const float*)d_in[1];
    const float* fb  = (const float*)d_in[2];
    const float* gw1 = (const float*)d_in[3];
    const float* gb1 = (const float*)d_in[4];
    const float* lng = (const float*)d_in[5];
    const float* lnb = (const float*)d_in[6];
    const float* gw2 = (const float*)d_in[7];
    const float* gb2 = (const float*)d_in[8];
    const float* we0 = (const float*)d_in[9];
    const float* be0 = (const float*)d_in[10];
    const float* wm  = (const float*)d_in[11];
    const float* bm  = (const float*)d_in[12];
    const float* wl  = (const float*)d_in[13];
    const float* bl  = (const float*)d_in[14];
    float* out = (float*)d_out;

    char* ws = (char*)d_ws;
    int* counts           = (int*)ws;                        // 64
    int* buckets          = (int*)(ws + 64);                 // 8*NPTS*4 = 8388608
    uint4* packA          = (uint4*)(ws + 8388672);          // 196608
    float* biasS          = (float*)(ws + 8585280);          // 6144
    int* blkcnt           = (int*)(ws + 8591424);            // 65536
    int* baseoff          = (int*)(ws + 8656960);            // 65536
    unsigned char* sel    = (unsigned char*)(ws + 8722496);  // 262144
    uint4* packGW1H       = (uint4*)(ws + 8984640);          // 8192
    uint4* packGW1L       = (uint4*)(ws + 8992832);          // 8192
    uint4* packGW2H       = (uint4*)(ws + 9001024);          // 2048
    uint4* packGW2L       = (uint4*)(ws + 9003072);          // 2048
    int* reflist          = (int*)(ws + 9005120);            // 1048576
    int* refcnt           = (int*)(ws + 10053696);           // 64

    hipMemsetAsync(d_out, 0, (size_t)(NPTS + 1) * sizeof(float), stream);
    hipMemsetAsync(refcnt, 0, 64, stream);

    prep_kernel<<<57, 256, 0, stream>>>(we0, be0, wm, bm, gw1, gw2, packA, biasS,
                                        packGW1H, packGW1L, packGW2H, packGW2L);
    gate_kernel<<<GBLK, 512, 0, stream>>>(coords, fw, fb, gb1, lng, lnb, gb2,
                                          packGW1H, packGW1L, packGW2H, packGW2L,
                                          sel, blkcnt, reflist, refcnt);
    refine_kernel<<<32, 256, 0, stream>>>(coords, fw, fb, gw1, gb1, lng, lnb, gw2, gb2,
                                          reflist, refcnt, sel, blkcnt);
    scan_kernel<<<1, 256, 0, stream>>>(blkcnt, baseoff, counts, out);
    scatter_kernel<<<GBLK, 128, 0, stream>>>(sel, baseoff, buckets);
    expert_kernel<<<8 * CPE, 256, 0, stream>>>(coords, fw, fb, wl, bl, packA, biasS,
                                               counts, buckets, out);
}

// Round 8
// 135.696 us; speedup vs baseline: 1.6185x; 1.0777x over previous
//
#include <hip/hip_runtime.h>
#include <math.h>

#define NPTS 262144
#define GBLK (NPTS / 128)     // 2048 gate blocks (128 points each)
#define CPE  2048             // chunks per expert in expert grid
#define TAU  0.01f            // refine margin threshold (logit units)

typedef float f4v __attribute__((ext_vector_type(4)));
typedef short s8v __attribute__((ext_vector_type(8)));

static __device__ __forceinline__ unsigned short f2bf(float f) {
    unsigned u = __float_as_uint(f);
    u += 0x7fffu + ((u >> 16) & 1u);
    return (unsigned short)(u >> 16);
}
static __device__ __forceinline__ float bf2f(unsigned short h) {
    return __uint_as_float(((unsigned)h) << 16);
}
static __device__ __forceinline__ unsigned pack2(float lo, float hi) {
    return ((unsigned)f2bf(hi) << 16) | (unsigned)f2bf(lo);
}
static __device__ __forceinline__ unsigned pk2b(unsigned short lo, unsigned short hi) {
    return ((unsigned)hi << 16) | (unsigned)lo;
}
static __device__ __forceinline__ float sinrev(float x) {   // sin(2*pi*x)
    return __builtin_amdgcn_sinf(x);
}

union BFrag { uint4 q; unsigned u[4]; s8v s; };

// ---------------- prep: pack expert A-frags + scaled biases + gate hi/lo packs ----------------
__global__ __launch_bounds__(256) void prep_kernel(
    const float* __restrict__ we0, const float* __restrict__ be0,
    const float* __restrict__ wm, const float* __restrict__ bm,
    const float* __restrict__ gw1, const float* __restrict__ gw2,
    uint4* __restrict__ packA, float* __restrict__ biasS,
    uint4* __restrict__ packGW1H, uint4* __restrict__ packGW1L,
    uint4* __restrict__ packGW2H, uint4* __restrict__ packGW2L)
{
    const int idx = blockIdx.x * 256 + threadIdx.x;
    const float PI2I = 0.15915494309189535f;
    if (idx < 12288) {
        const int l = idx & 63;
        const int fr = (idx >> 6) & 7;
        const int grp = idx >> 9;            // e*3 + ell
        const int e = grp / 3, ell = grp % 3;
        const int tau = fr >> 1, ks = fr & 1;
        const int g = l >> 4, m = l & 15;
        const int row = tau * 16 + m;
        const float scale = (ell == 0) ? (22.5f + 45.0f * (float)e) * PI2I : 30.0f * PI2I;
        const float* W = (ell == 0) ? (we0 + e * 4096) : (wm + ((ell - 1) * 8 + e) * 4096);
        unsigned short v[8];
#pragma unroll
        for (int i = 0; i < 8; i++) {
            const int k = 32 * ks + 4 * g + (i < 4 ? i : i + 12);
            v[i] = f2bf(W[row * 64 + k] * scale);
        }
        uint4 q;
        q.x = pk2b(v[0], v[1]); q.y = pk2b(v[2], v[3]);
        q.z = pk2b(v[4], v[5]); q.w = pk2b(v[6], v[7]);
        packA[idx] = q;
    } else if (idx < 13824) {
        const int j = idx - 12288;           // e*192 + ell*64 + r
        const int r = j & 63;
        const int grp = j >> 6;
        const int e = grp / 3, ell = grp % 3;
        const float scale = (ell == 0) ? (22.5f + 45.0f * (float)e) * PI2I : 30.0f * PI2I;
        const float b = (ell == 0) ? be0[e * 64 + r] : bm[((ell - 1) * 8 + e) * 64 + r];
        biasS[j] = b * scale;
    } else if (idx < 14336) {
        // gate gw1 hi/lo A-frags: 8 frags (tau*2+ks) x 64 lanes
        const int j = idx - 13824;           // 0..511
        const int l = j & 63;
        const int fr = j >> 6;
        const int tau = fr >> 1, ks = fr & 1;
        const int g = l >> 4;
        const int row = tau * 16 + (l & 15);
        unsigned short vh[8], vl[8];
#pragma unroll
        for (int i = 0; i < 8; i++) {
            const int k = 32 * ks + 4 * g + (i < 4 ? i : i + 12);
            const float x = gw1[row * 64 + k];
            const unsigned short h = f2bf(x);
            vh[i] = h;
            vl[i] = f2bf(x - bf2f(h));
        }
        uint4 qh, ql;
        qh.x = pk2b(vh[0], vh[1]); qh.y = pk2b(vh[2], vh[3]);
        qh.z = pk2b(vh[4], vh[5]); qh.w = pk2b(vh[6], vh[7]);
        ql.x = pk2b(vl[0], vl[1]); ql.y = pk2b(vl[2], vl[3]);
        ql.z = pk2b(vl[4], vl[5]); ql.w = pk2b(vl[6], vl[7]);
        packGW1H[j] = qh; packGW1L[j] = ql;
    } else if (idx < 14464) {
        // gate gw2 hi/lo A-frags: rows 0..7 = gw2, rows 8..15 = 0; 2 frags (ks) x 64 lanes
        const int j = idx - 14336;           // 0..127
        const int l = j & 63;
        const int ks = j >> 6;
        const int g = l >> 4;
        const int row = l & 15;
        unsigned short vh[8], vl[8];
#pragma unroll
        for (int i = 0; i < 8; i++) {
            const int k = 32 * ks + 4 * g + (i < 4 ? i : i + 12);
            const float x = (row < 8) ? gw2[row * 64 + k] : 0.f;
            const unsigned short h = f2bf(x);
            vh[i] = h;
            vl[i] = f2bf(x - bf2f(h));
        }
        uint4 qh, ql;
        qh.x = pk2b(vh[0], vh[1]); qh.y = pk2b(vh[2], vh[3]);
        qh.z = pk2b(vh[4], vh[5]); qh.w = pk2b(vh[6], vh[7]);
        ql.x = pk2b(vl[0], vl[1]); ql.y = pk2b(vl[2], vl[3]);
        ql.z = pk2b(vl[4], vl[5]); ql.w = pk2b(vl[6], vl[7]);
        packGW2H[j] = qh; packGW2L[j] = ql;
    }
}

// ---------------- K1: gate via MFMA (hi/lo split) + margin flag for refine ----------------
// 512 threads = 8 waves x 16 points = 128 points per block.
__global__ __launch_bounds__(512) void gate_kernel(
    const float* __restrict__ coords,
    const float* __restrict__ fw, const float* __restrict__ fb,
    const float* __restrict__ gb1, const float* __restrict__ lng,
    const float* __restrict__ lnb, const float* __restrict__ gb2,
    const uint4* __restrict__ packGW1H, const uint4* __restrict__ packGW1L,
    const uint4* __restrict__ packGW2H, const uint4* __restrict__ packGW2L,
    unsigned char* __restrict__ sel, int* __restrict__ blkcnt,
    int* __restrict__ reflist, int* __restrict__ refcnt)
{
    __shared__ float s_fw[192], s_fb[64], s_gb1[64], s_lng[64], s_lnb[64], s_gb2[8];
    __shared__ int s_cnt[8];
    const int t = threadIdx.x;
    if (t < 192) s_fw[t] = fw[t];
    if (t < 64) { s_fb[t] = fb[t]; s_gb1[t] = gb1[t]; s_lng[t] = lng[t]; s_lnb[t] = lnb[t]; }
    if (t < 8) { s_gb2[t] = gb2[t]; s_cnt[t] = 0; }
    __syncthreads();

    const int lane = t & 63;
    const int wv = t >> 6;
    const int g = lane >> 4, c = lane & 15;
    const int n = blockIdx.x * 128 + wv * 16 + c;

    // ---- features: this lane's 16 k-values of point n (fp32, exact order) ----
    const float c0 = coords[n * 3], c1 = coords[n * 3 + 1], c2 = coords[n * 3 + 2];
    float fv[16];
#pragma unroll
    for (int s = 0; s < 4; s++) {
#pragma unroll
        for (int j = 0; j < 4; j++) {
            const int k = 16 * s + 4 * g + j;
            fv[s * 4 + j] = s_fb[k] + c0 * s_fw[k * 3] + c1 * s_fw[k * 3 + 1] + c2 * s_fw[k * 3 + 2];
        }
    }
    unsigned short fh[16]; float fl[16];
#pragma unroll
    for (int i = 0; i < 16; i++) {
        fh[i] = f2bf(fv[i]);
        fl[i] = fv[i] - bf2f(fh[i]);
    }
    BFrag Bh[2], Bl[2];
#pragma unroll
    for (int ks = 0; ks < 2; ks++) {
#pragma unroll
        for (int q = 0; q < 4; q++) {
            Bh[ks].u[q] = pk2b(fh[ks * 8 + 2 * q], fh[ks * 8 + 2 * q + 1]);
            Bl[ks].u[q] = pack2(fl[ks * 8 + 2 * q], fl[ks * 8 + 2 * q + 1]);
        }
    }

    // ---- g = gw1 @ f + gb1 via 3-term MFMA ----
    f4v acc[4];
#pragma unroll
    for (int tau = 0; tau < 4; tau++) {
        const float4 b = *(const float4*)&s_gb1[tau * 16 + 4 * g];
        acc[tau][0] = b.x; acc[tau][1] = b.y; acc[tau][2] = b.z; acc[tau][3] = b.w;
    }
#pragma unroll
    for (int tau = 0; tau < 4; tau++) {
        BFrag AH0, AH1, AL0, AL1;
        AH0.q = packGW1H[(tau * 2 + 0) * 64 + lane];
        AH1.q = packGW1H[(tau * 2 + 1) * 64 + lane];
        AL0.q = packGW1L[(tau * 2 + 0) * 64 + lane];
        AL1.q = packGW1L[(tau * 2 + 1) * 64 + lane];
        acc[tau] = __builtin_amdgcn_mfma_f32_16x16x32_bf16(AH0.s, Bh[0].s, acc[tau], 0, 0, 0);
        acc[tau] = __builtin_amdgcn_mfma_f32_16x16x32_bf16(AH1.s, Bh[1].s, acc[tau], 0, 0, 0);
        acc[tau] = __builtin_amdgcn_mfma_f32_16x16x32_bf16(AH0.s, Bl[0].s, acc[tau], 0, 0, 0);
        acc[tau] = __builtin_amdgcn_mfma_f32_16x16x32_bf16(AH1.s, Bl[1].s, acc[tau], 0, 0, 0);
        acc[tau] = __builtin_amdgcn_mfma_f32_16x16x32_bf16(AL0.s, Bh[0].s, acc[tau], 0, 0, 0);
        acc[tau] = __builtin_amdgcn_mfma_f32_16x16x32_bf16(AL1.s, Bh[1].s, acc[tau], 0, 0, 0);
    }

    // ---- LayerNorm over the 64 rows (cross-lane over g groups) ----
    float s1 = 0.f;
#pragma unroll
    for (int tau = 0; tau < 4; tau++)
#pragma unroll
        for (int j = 0; j < 4; j++) s1 += acc[tau][j];
    s1 += __shfl_xor(s1, 16, 64); s1 += __shfl_xor(s1, 32, 64);
    const float mu = s1 * (1.f / 64.f);
    float s2 = 0.f;
#pragma unroll
    for (int tau = 0; tau < 4; tau++)
#pragma unroll
        for (int j = 0; j < 4; j++) { const float d = acc[tau][j] - mu; s2 += d * d; }
    s2 += __shfl_xor(s2, 16, 64); s2 += __shfl_xor(s2, 32, 64);
    const float rs = rsqrtf(s2 * (1.f / 64.f) + 1e-5f);

    float gn[16];
#pragma unroll
    for (int tau = 0; tau < 4; tau++) {
        const float4 lg = *(const float4*)&s_lng[tau * 16 + 4 * g];
        const float4 lb = *(const float4*)&s_lnb[tau * 16 + 4 * g];
        gn[tau * 4 + 0] = (acc[tau][0] - mu) * rs * lg.x + lb.x;
        gn[tau * 4 + 1] = (acc[tau][1] - mu) * rs * lg.y + lb.y;
        gn[tau * 4 + 2] = (acc[tau][2] - mu) * rs * lg.z + lb.z;
        gn[tau * 4 + 3] = (acc[tau][3] - mu) * rs * lg.w + lb.w;
    }
    // D->B repack of gn (proven mapping) with hi/lo split
    unsigned short gh[16]; float gl[16];
#pragma unroll
    for (int i = 0; i < 16; i++) { gh[i] = f2bf(gn[i]); gl[i] = gn[i] - bf2f(gh[i]); }
    BFrag Gh[2], Gl[2];
#pragma unroll
    for (int ks = 0; ks < 2; ks++) {
        Gh[ks].u[0] = pk2b(gh[(2 * ks) * 4 + 0], gh[(2 * ks) * 4 + 1]);
        Gh[ks].u[1] = pk2b(gh[(2 * ks) * 4 + 2], gh[(2 * ks) * 4 + 3]);
        Gh[ks].u[2] = pk2b(gh[(2 * ks + 1) * 4 + 0], gh[(2 * ks + 1) * 4 + 1]);
        Gh[ks].u[3] = pk2b(gh[(2 * ks + 1) * 4 + 2], gh[(2 * ks + 1) * 4 + 3]);
        Gl[ks].u[0] = pack2(gl[(2 * ks) * 4 + 0], gl[(2 * ks) * 4 + 1]);
        Gl[ks].u[1] = pack2(gl[(2 * ks) * 4 + 2], gl[(2 * ks) * 4 + 3]);
        Gl[ks].u[2] = pack2(gl[(2 * ks + 1) * 4 + 0], gl[(2 * ks + 1) * 4 + 1]);
        Gl[ks].u[3] = pack2(gl[(2 * ks + 1) * 4 + 2], gl[(2 * ks + 1) * 4 + 3]);
    }

    // ---- logits = gw2 @ gn via 3-term MFMA (rows 0..7 valid) ----
    f4v lacc = {0.f, 0.f, 0.f, 0.f};
    BFrag W0, W1, V0, V1;
    W0.q = packGW2H[0 * 64 + lane]; W1.q = packGW2H[1 * 64 + lane];
    V0.q = packGW2L[0 * 64 + lane]; V1.q = packGW2L[1 * 64 + lane];
    lacc = __builtin_amdgcn_mfma_f32_16x16x32_bf16(W0.s, Gh[0].s, lacc, 0, 0, 0);
    lacc = __builtin_amdgcn_mfma_f32_16x16x32_bf16(W1.s, Gh[1].s, lacc, 0, 0, 0);
    lacc = __builtin_amdgcn_mfma_f32_16x16x32_bf16(W0.s, Gl[0].s, lacc, 0, 0, 0);
    lacc = __builtin_amdgcn_mfma_f32_16x16x32_bf16(W1.s, Gl[1].s, lacc, 0, 0, 0);
    lacc = __builtin_amdgcn_mfma_f32_16x16x32_bf16(V0.s, Gh[0].s, lacc, 0, 0, 0);
    lacc = __builtin_amdgcn_mfma_f32_16x16x32_bf16(V1.s, Gh[1].s, lacc, 0, 0, 0);

    float other[4];
#pragma unroll
    for (int j = 0; j < 4; j++) other[j] = __shfl_xor(lacc[j], 16, 64);
    float logit[8];
#pragma unroll
    for (int j = 0; j < 4; j++) {
        logit[j] = lacc[j] + s_gb2[j];          // valid on g==0 lanes (rows 0..3)
        logit[4 + j] = other[j] + s_gb2[4 + j]; // rows 4..7 from g==1 partner
    }

    // ---- top-2 (>= 2nd-largest semantics) + margin flag ----
    float m1 = logit[0]; int i1 = 0;
#pragma unroll
    for (int e = 1; e < 8; e++) if (logit[e] > m1) { m1 = logit[e]; i1 = e; }
    float m2 = -INFINITY; int i2 = -1;
#pragma unroll
    for (int e = 0; e < 8; e++) if (e != i1 && logit[e] > m2) { m2 = logit[e]; i2 = e; }
    float m3 = -INFINITY;
#pragma unroll
    for (int e = 0; e < 8; e++) if (e != i1 && e != i2 && logit[e] > m3) m3 = logit[e];
    unsigned mbits = 0;
#pragma unroll
    for (int e = 0; e < 8; e++) if (logit[e] >= m2) mbits |= 1u << e;

    const bool active = (g == 0);
    if (active) sel[n] = (unsigned char)mbits;
    const bool flg = active && (m2 - m3 < TAU);

#pragma unroll
    for (int e = 0; e < 8; e++) {
        const unsigned long long bal = __ballot(active && ((mbits >> e) & 1u));
        if (lane == 0) atomicAdd(&s_cnt[e], (int)__popcll(bal));
    }
    {
        const unsigned long long bal = __ballot(flg);
        int pos0 = 0;
        if (lane == 0 && bal) pos0 = atomicAdd(refcnt, (int)__popcll(bal));
        pos0 = __shfl(pos0, 0, 64);
        if (flg) {
            const int rank = (int)__popcll(bal & ((1ull << lane) - 1ull));
            reflist[pos0 + rank] = n;
        }
    }
    __syncthreads();
    if (t < 8) blkcnt[blockIdx.x * 8 + t] = s_cnt[t];
}

// ---------------- K1.25: exact-fp32 refine, ONE WAVE PER POINT (no scratch arrays) ----------------
__global__ __launch_bounds__(256) void refine_kernel(
    const float* __restrict__ coords,
    const float* __restrict__ fw, const float* __restrict__ fb,
    const float* __restrict__ gw1, const float* __restrict__ gb1,
    const float* __restrict__ lng, const float* __restrict__ lnb,
    const float* __restrict__ gw2, const float* __restrict__ gb2,
    const int* __restrict__ reflist, const int* __restrict__ refcnt,
    unsigned char* __restrict__ sel, int* __restrict__ blkcnt)
{
    const int R = *refcnt;
    if (blockIdx.x * 4 >= R) return;            // uniform early exit, before any barrier

    __shared__ float s_gw1t[64 * 65];           // transposed + pad: [k][r] at k*65+r
    __shared__ float s_gw2[512];
    __shared__ float s_fw[192], s_fb[64], s_gb1[64], s_lng[64], s_lnb[64], s_gb2[8];
    __shared__ float s_f[4][64];                // per-wave feature buffer

    const int t = threadIdx.x;
    for (int i = t; i < 4096; i += 256) s_gw1t[(i & 63) * 65 + (i >> 6)] = gw1[i];
    for (int i = t; i < 512; i += 256) s_gw2[i] = gw2[i];
    if (t < 192) s_fw[t] = fw[t];
    if (t < 64) { s_fb[t] = fb[t]; s_gb1[t] = gb1[t]; s_lng[t] = lng[t]; s_lnb[t] = lnb[t]; }
    if (t < 8) s_gb2[t] = gb2[t];
    __syncthreads();

    const int wv = t >> 6, lane = t & 63;
    for (int idx = blockIdx.x * 4 + wv; idx < R; idx += gridDim.x * 4) {
        const int n = reflist[idx];
        const float c0 = coords[n * 3], c1 = coords[n * 3 + 1], c2 = coords[n * 3 + 2];
        // lane computes feature[lane]; intra-wave LDS RAW is in-order (no barrier needed)
        const float fr = s_fb[lane] + c0 * s_fw[lane * 3] + c1 * s_fw[lane * 3 + 1]
                       + c2 * s_fw[lane * 3 + 2];
        s_f[wv][lane] = fr;
        // gate row = lane: 64 MACs (f broadcast, gw1t conflict-free)
        float a = s_gb1[lane];
#pragma unroll
        for (int k = 0; k < 64; k++)
            a += s_f[wv][k] * s_gw1t[k * 65 + lane];
        // LN stats via butterfly
        float mu = a;
#pragma unroll
        for (int d = 1; d < 64; d <<= 1) mu += __shfl_xor(mu, d, 64);
        mu *= (1.f / 64.f);
        const float dv = a - mu;
        float v = dv * dv;
#pragma unroll
        for (int d = 1; d < 64; d <<= 1) v += __shfl_xor(v, d, 64);
        const float rs = rsqrtf(v * (1.f / 64.f) + 1e-5f);
        const float gn = dv * rs * s_lng[lane] + s_lnb[lane];
        // logits: per-lane partials + butterfly reduce
        float lp[8];
#pragma unroll
        for (int e = 0; e < 8; e++) lp[e] = gn * s_gw2[e * 64 + lane];
#pragma unroll
        for (int e = 0; e < 8; e++) {
#pragma unroll
            for (int d = 1; d < 64; d <<= 1) lp[e] += __shfl_xor(lp[e], d, 64);
            lp[e] += s_gb2[e];
        }
        if (lane == 0) {
            float m1 = lp[0]; int i1 = 0;
#pragma unroll
            for (int e = 1; e < 8; e++) if (lp[e] > m1) { m1 = lp[e]; i1 = e; }
            float m2 = -INFINITY;
#pragma unroll
            for (int e = 0; e < 8; e++) if (e != i1 && lp[e] > m2) m2 = lp[e];
            unsigned mbits = 0;
#pragma unroll
            for (int e = 0; e < 8; e++) if (lp[e] >= m2) mbits |= 1u << e;
            const unsigned old = sel[n];
            if (mbits != old) {
                sel[n] = (unsigned char)mbits;
                const int b = n >> 7;
#pragma unroll
                for (int e = 0; e < 8; e++) {
                    const int was = (old >> e) & 1, now = (mbits >> e) & 1;
                    if (was != now) atomicAdd(&blkcnt[b * 8 + e], now - was);
                }
            }
        }
    }
}

// ---------------- K1.5: single-block scan -> baseoff, counts, aux ----------------
__global__ __launch_bounds__(256) void scan_kernel(
    const int* __restrict__ blkcnt, int* __restrict__ baseoff,
    int* __restrict__ counts, float* __restrict__ out)
{
    __shared__ int s_tot[8];
    const int t = threadIdx.x;
    const int e = t >> 5;        // 8 experts x 32 lanes
    const int q = t & 31;
    const int b0 = q * (GBLK / 32);
    int partial = 0;
    for (int b = b0; b < b0 + GBLK / 32; b++) partial += blkcnt[b * 8 + e];
    int incl = partial;
#pragma unroll
    for (int d = 1; d < 32; d <<= 1) {
        const int v = __shfl_up(incl, d, 32);
        if (q >= d) incl += v;
    }
    const int excl = incl - partial;
    const int total = __shfl(incl, 31, 32);
    if (q == 0) { counts[e] = total; s_tot[e] = total; }
    int run = excl;
    for (int b = b0; b < b0 + GBLK / 32; b++) {
        baseoff[b * 8 + e] = run;
        run += blkcnt[b * 8 + e];
    }
    __syncthreads();
    if (t == 0) {
        double s = 0.0;
        for (int i = 0; i < 8; i++) { const double c = (double)s_tot[i]; s += c * c; }
        out[NPTS] = (float)(8.0 * s / ((double)NPTS * (double)NPTS));
    }
}

// ---------------- K2: scatter points into buckets (no atomics) ----------------
__global__ __launch_bounds__(128) void scatter_kernel(
    const unsigned char* __restrict__ sel, const int* __restrict__ baseoff,
    int* __restrict__ buckets)
{
    __shared__ int s_w0[8];
    const int t = threadIdx.x;
    const int n = blockIdx.x * 128 + t;
    const unsigned m = sel[n];
    const int w = t >> 6, lane = t & 63;
    unsigned long long bal[8];
#pragma unroll
    for (int e = 0; e < 8; e++) {
        bal[e] = __ballot((m >> e) & 1u);
        if (w == 0 && lane == 0) s_w0[e] = (int)__popcll(bal[e]);
    }
    __syncthreads();
#pragma unroll
    for (int e = 0; e < 8; e++) {
        if ((m >> e) & 1u) {
            int rank = (int)__popcll(bal[e] & ((1ull << lane) - 1ull));
            if (w == 1) rank += s_w0[e];
            buckets[e * NPTS + baseoff[blockIdx.x * 8 + e] + rank] = n;
        }
    }
}

// ---------------- K3: per-expert MFMA SIREN on gathered bucket entries ----------------
__global__ __launch_bounds__(256) void expert_kernel(
    const float* __restrict__ coords,
    const float* __restrict__ fw, const float* __restrict__ fb,
    const float* __restrict__ wl, const float* __restrict__ bl,
    const uint4* __restrict__ packA, const float* __restrict__ biasS,
    const int* __restrict__ counts, const int* __restrict__ buckets,
    float* __restrict__ out)
{
    const int e = blockIdx.x >> 11;            // CPE == 2048
    const int chunk = blockIdx.x & (CPE - 1);
    const int cnt = counts[e];
    const int base = chunk * 128;
    if (base >= cnt) return;

    __shared__ unsigned char s_ft[16 * 1024];
    __shared__ int s_id[128];
    __shared__ float s_b[192];
    __shared__ float s_wl[64];
    __shared__ float s_fw[192];
    __shared__ float s_fb[64];
    __shared__ float s_bl;

    const int t = threadIdx.x;
    if (t < 128) {
        const int gid = base + t;
        s_id[t] = (gid < cnt) ? buckets[e * NPTS + gid] : -1;
    }
    if (t < 192) {
        s_b[t] = biasS[e * 192 + t];
        s_fw[t] = fw[t];
    }
    if (t < 64) {
        s_fb[t] = fb[t];
        s_wl[t] = wl[e * 64 + t];
    }
    if (t == 0) s_bl = bl[e];
    __syncthreads();

    const int half = t & 1;
    const int p = t >> 1;
    const int id_p = s_id[p];
    float fh[32];
    if (id_p >= 0) {
        const float c0 = coords[id_p * 3], c1 = coords[id_p * 3 + 1], c2 = coords[id_p * 3 + 2];
        if (half == 0) {
#pragma unroll
            for (int j = 0; j < 32; j++)
                fh[j] = s_fb[j] + c0 * s_fw[j * 3] + c1 * s_fw[j * 3 + 1] + c2 * s_fw[j * 3 + 2];
        } else {
#pragma unroll
            for (int j = 0; j < 32; j++) {
                const int row = j + 32;
                fh[j] = s_fb[row] + c0 * s_fw[row * 3] + c1 * s_fw[row * 3 + 1] + c2 * s_fw[row * 3 + 2];
            }
        }
    } else {
#pragma unroll
        for (int j = 0; j < 32; j++) fh[j] = 0.f;
    }
    {
        const int region = ((p >> 5) * 2 + ((p >> 4) & 1)) * 2 + half;
        const int slotc = p & 15;
#pragma unroll
        for (int g = 0; g < 4; g++) {
            uint4 q;
            q.x = pack2(fh[4 * g + 0], fh[4 * g + 1]);
            q.y = pack2(fh[4 * g + 2], fh[4 * g + 3]);
            q.z = pack2(fh[4 * g + 16], fh[4 * g + 17]);
            q.w = pack2(fh[4 * g + 18], fh[4 * g + 19]);
            *(uint4*)&s_ft[region * 1024 + (16 * g + slotc) * 16] = q;
        }
    }
    __syncthreads();

    const int lane = t & 63;
    const int wv = t >> 6;
    const int g = lane >> 4, c = lane & 15;
    const int id0 = s_id[wv * 32 + c];
    const int id1 = s_id[wv * 32 + 16 + c];

    BFrag B0[2], B1[2];
#pragma unroll
    for (int ks = 0; ks < 2; ks++) {
        B0[ks].q = *(const uint4*)&s_ft[(((wv * 2 + 0) * 2 + ks) * 1024) + lane * 16];
        B1[ks].q = *(const uint4*)&s_ft[(((wv * 2 + 1) * 2 + ks) * 1024) + lane * 16];
    }

#pragma unroll 1
    for (int ell = 0; ell < 2; ell++) {
        f4v acc0[4], acc1[4];
#pragma unroll
        for (int tau = 0; tau < 4; tau++) {
            const float4 b = *(const float4*)&s_b[ell * 64 + tau * 16 + 4 * g];
            acc0[tau][0] = b.x; acc0[tau][1] = b.y; acc0[tau][2] = b.z; acc0[tau][3] = b.w;
            acc1[tau][0] = b.x; acc1[tau][1] = b.y; acc1[tau][2] = b.z; acc1[tau][3] = b.w;
        }
        const uint4* Ab = packA + (size_t)((e * 3 + ell) * 8) * 64 + lane;
#pragma unroll
        for (int tau = 0; tau < 4; tau++) {
            BFrag A0, A1;
            A0.q = Ab[(tau * 2 + 0) * 64];
            A1.q = Ab[(tau * 2 + 1) * 64];
            acc0[tau] = __builtin_amdgcn_mfma_f32_16x16x32_bf16(A0.s, B0[0].s, acc0[tau], 0, 0, 0);
            acc0[tau] = __builtin_amdgcn_mfma_f32_16x16x32_bf16(A1.s, B0[1].s, acc0[tau], 0, 0, 0);
            acc1[tau] = __builtin_amdgcn_mfma_f32_16x16x32_bf16(A0.s, B1[0].s, acc1[tau], 0, 0, 0);
            acc1[tau] = __builtin_amdgcn_mfma_f32_16x16x32_bf16(A1.s, B1[1].s, acc1[tau], 0, 0, 0);
        }
#pragma unroll
        for (int ks = 0; ks < 2; ks++) {
            B0[ks].u[0] = pack2(sinrev(acc0[2 * ks][0]), sinrev(acc0[2 * ks][1]));
            B0[ks].u[1] = pack2(sinrev(acc0[2 * ks][2]), sinrev(acc0[2 * ks][3]));
            B0[ks].u[2] = pack2(sinrev(acc0[2 * ks + 1][0]), sinrev(acc0[2 * ks + 1][1]));
            B0[ks].u[3] = pack2(sinrev(acc0[2 * ks + 1][2]), sinrev(acc0[2 * ks + 1][3]));
            B1[ks].u[0] = pack2(sinrev(acc1[2 * ks][0]), sinrev(acc1[2 * ks][1]));
            B1[ks].u[1] = pack2(sinrev(acc1[2 * ks][2]), sinrev(acc1[2 * ks][3]));
            B1[ks].u[2] = pack2(sinrev(acc1[2 * ks + 1][0]), sinrev(acc1[2 * ks + 1][1]));
            B1[ks].u[3] = pack2(sinrev(acc1[2 * ks + 1][2]), sinrev(acc1[2 * ks + 1][3]));
        }
    }

    {
        f4v acc0[4], acc1[4];
#pragma unroll
        for (int tau = 0; tau < 4; tau++) {
            const float4 b = *(const float4*)&s_b[2 * 64 + tau * 16 + 4 * g];
            acc0[tau][0] = b.x; acc0[tau][1] = b.y; acc0[tau][2] = b.z; acc0[tau][3] = b.w;
            acc1[tau][0] = b.x; acc1[tau][1] = b.y; acc1[tau][2] = b.z; acc1[tau][3] = b.w;
        }
        const uint4* Ab = packA + (size_t)((e * 3 + 2) * 8) * 64 + lane;
#pragma unroll
        for (int tau = 0; tau < 4; tau++) {
            BFrag A0, A1;
            A0.q = Ab[(tau * 2 + 0) * 64];
            A1.q = Ab[(tau * 2 + 1) * 64];
            acc0[tau] = __builtin_amdgcn_mfma_f32_16x16x32_bf16(A0.s, B0[0].s, acc0[tau], 0, 0, 0);
            acc0[tau] = __builtin_amdgcn_mfma_f32_16x16x32_bf16(A1.s, B0[1].s, acc0[tau], 0, 0, 0);
            acc1[tau] = __builtin_amdgcn_mfma_f32_16x16x32_bf16(A0.s, B1[0].s, acc1[tau], 0, 0, 0);
            acc1[tau] = __builtin_amdgcn_mfma_f32_16x16x32_bf16(A1.s, B1[1].s, acc1[tau], 0, 0, 0);
        }
        float px0 = 0.f, px1 = 0.f;
#pragma unroll
        for (int tau = 0; tau < 4; tau++) {
            const float4 w = *(const float4*)&s_wl[tau * 16 + 4 * g];
            px0 += sinrev(acc0[tau][0]) * w.x + sinrev(acc0[tau][1]) * w.y
                 + sinrev(acc0[tau][2]) * w.z + sinrev(acc0[tau][3]) * w.w;
            px1 += sinrev(acc1[tau][0]) * w.x + sinrev(acc1[tau][1]) * w.y
                 + sinrev(acc1[tau][2]) * w.z + sinrev(acc1[tau][3]) * w.w;
        }
        px0 += __shfl_xor(px0, 16, 64); px0 += __shfl_xor(px0, 32, 64);
        px1 += __shfl_xor(px1, 16, 64); px1 += __shfl_xor(px1, 32, 64);
        if (g == 0) {
            if (id0 >= 0) atomicAdd(&out[id0], px0 + s_bl);
            if (id1 >= 0) atomicAdd(&out[id1], px1 + s_bl);
        }
    }
}

extern "C" void kernel_launch(void* const* d_in, const int* in_sizes, int n_in,
                              void* d_out, int out_size, void* d_ws, size_t ws_size,
                              hipStream_t stream)
{
    const float* coords = (const float*)d_in[0];
    const float* fw  = (const float*)d_in[1];
    const float* fb  = (const float*)d_in[2];
    const float* gw1 = (const float*)d_in[3];
    const float* gb1 = (const float*)d_in[4];
    const float* lng = (const float*)d_in[5];
    const float* lnb = (const float*)d_in[6];
    const float* gw2 = (const float*)d_in[7];
    const float* gb2 = (const float*)d_in[8];
    const float* we0 = (const float*)d_in[9];
    const float* be0 = (const float*)d_in[10];
    const float* wm  = (const float*)d_in[11];
    const float* bm  = (const float*)d_in[12];
    const float* wl  = (const float*)d_in[13];
    const float* bl  = (const float*)d_in[14];
    float* out = (float*)d_out;

    char* ws = (char*)d_ws;
    int* counts           = (int*)ws;                        // 64
    int* buckets          = (int*)(ws + 64);                 // 8*NPTS*4 = 8388608
    uint4* packA          = (uint4*)(ws + 8388672);          // 196608
    float* biasS          = (float*)(ws + 8585280);          // 6144
    int* blkcnt           = (int*)(ws + 8591424);            // 65536
    int* baseoff          = (int*)(ws + 8656960);            // 65536
    unsigned char* sel    = (unsigned char*)(ws + 8722496);  // 262144
    uint4* packGW1H       = (uint4*)(ws + 8984640);          // 8192
    uint4* packGW1L       = (uint4*)(ws + 8992832);          // 8192
    uint4* packGW2H       = (uint4*)(ws + 9001024);          // 2048
    uint4* packGW2L       = (uint4*)(ws + 9003072);          // 2048
    int* reflist          = (int*)(ws + 9005120);            // 1048576
    int* refcnt           = (int*)(ws + 10053696);           // 64

    hipMemsetAsync(d_out, 0, (size_t)(NPTS + 1) * sizeof(float), stream);
    hipMemsetAsync(refcnt, 0, 64, stream);

    prep_kernel<<<57, 256, 0, stream>>>(we0, be0, wm, bm, gw1, gw2, packA, biasS,
                                        packGW1H, packGW1L, packGW2H, packGW2L);
    gate_kernel<<<GBLK, 512, 0, stream>>>(coords, fw, fb, gb1, lng, lnb, gb2,
                                          packGW1H, packGW1L, packGW2H, packGW2L,
                                          sel, blkcnt, reflist, refcnt);
    refine_kernel<<<128, 256, 0, stream>>>(coords, fw, fb, gw1, gb1, lng, lnb, gw2, gb2,
                                           reflist, refcnt, sel, blkcnt);
    scan_kernel<<<1, 256, 0, stream>>>(blkcnt, baseoff, counts, out);
    scatter_kernel<<<GBLK, 128, 0, stream>>>(sel, baseoff, buckets);
    expert_kernel<<<8 * CPE, 256, 0, stream>>>(coords, fw, fb, wl, bl, packA, biasS,
                                               counts, buckets, out);
}